// Round 2
// baseline (126.576 us; speedup 1.0000x reference)
//
#include <hip/hip_runtime.h>

// Chamfer (bidirectional 1-NN mean of squared distances), two [16384,3] fp32 clouds.
// d(i,j) = |a_i|^2 + (|b_j|^2 - 2 a_i.b_j); row-min taken on t(j)=|b_j|^2-2a.b_j.
//
// Round-2 changes vs round-1:
//  - Inner loop processes 2 B-points per step via packed fp32 (v_pk_fma_f32,
//    ext_vector float2 + __builtin_elementwise_fma) and merges both lanes +
//    running min with one v_min3_f32: ~2.1 VALU instr/pair vs 4.0.
//  - LDS B-chunk stored pre-paired: sB[2p]={x0,x1,y0,y1}, sB[2p+1]={z0,z1,w0,w1}
//    so packed operands come straight out of ds_read_b128 halves (no shuffles).
//  - Reduce fused into the min kernel (last-block-reduces). The arrival counter
//    shares the 0x7F memset: it counts up from 0x7F7F7F7F (wrap-free, 1024 adds).

typedef float f32x2 __attribute__((ext_vector_type(2)));
typedef float f32x4 __attribute__((ext_vector_type(4)));

#define NPTS 16384
#define CHUNK 512
#define NCHUNKS (NPTS / CHUNK)          // 32
#define MPTS 4                          // A-points per thread
#define BLOCK 256
#define APT (BLOCK * MPTS)              // 1024 A-points per block
#define NATILES (NPTS / APT)            // 16
#define NBLOCKS (NATILES * NCHUNKS * 2) // 1024
#define CINIT 0x7F7F7F7Fu

__global__ __launch_bounds__(BLOCK) void chamfer_fused(
    const float* __restrict__ P0, const float* __restrict__ P1,
    unsigned* __restrict__ dmin_all, unsigned* __restrict__ counter,
    float* __restrict__ out)
{
    const float* A;
    const float* B;
    unsigned* dmin;
    if (blockIdx.z == 0) { A = P0; B = P1; dmin = dmin_all; }
    else                 { A = P1; B = P0; dmin = dmin_all + NPTS; }

    __shared__ f32x4 sB[CHUNK];   // pair p: sB[2p]={x0,x1,y0,y1}, sB[2p+1]={z0,z1,w0,w1}

    const int tid = threadIdx.x;

    // Stage this B-chunk (512 points = 256 pairs; one pair per thread), pre-transformed:
    // x,y,z scaled by -2; w = |b|^2.
    {
        const int j0 = (blockIdx.y * CHUNK + 2 * tid) * 3;
        const float x0 = B[j0 + 0], y0 = B[j0 + 1], z0 = B[j0 + 2];
        const float x1 = B[j0 + 3], y1 = B[j0 + 4], z1 = B[j0 + 5];
        sB[2 * tid]     = (f32x4){-2.f * x0, -2.f * x1, -2.f * y0, -2.f * y1};
        sB[2 * tid + 1] = (f32x4){-2.f * z0, -2.f * z1,
                                  x0 * x0 + y0 * y0 + z0 * z0,
                                  x1 * x1 + y1 * y1 + z1 * z1};
    }
    __syncthreads();

    // 4 A-points per thread, coordinates splatted for packed math.
    f32x2 ax2[MPTS], ay2[MPTS], az2[MPTS];
    float a2[MPTS], tmin[MPTS];
    const int ibase = blockIdx.x * APT + tid * MPTS;
#pragma unroll
    for (int m = 0; m < MPTS; ++m) {
        const float x = A[(ibase + m) * 3 + 0];
        const float y = A[(ibase + m) * 3 + 1];
        const float z = A[(ibase + m) * 3 + 2];
        ax2[m] = (f32x2){x, x};
        ay2[m] = (f32x2){y, y};
        az2[m] = (f32x2){z, z};
        a2[m]  = x * x + y * y + z * z;
        tmin[m] = 3.0e38f;
    }

    // Inner loop: per 2 B-points -> 2 broadcast ds_read_b128, then per A-point:
    // 3 v_pk_fma_f32 + 1 v_min3_f32  (2.06 VALU instr per pair).
#pragma unroll 4
    for (int p = 0; p < CHUNK / 2; ++p) {
        const f32x4 bxy = sB[2 * p];
        const f32x4 bzw = sB[2 * p + 1];
#pragma unroll
        for (int m = 0; m < MPTS; ++m) {
            f32x2 t = __builtin_elementwise_fma(az2[m], bzw.xy, bzw.zw);
            t = __builtin_elementwise_fma(ay2[m], bxy.zw, t);
            t = __builtin_elementwise_fma(ax2[m], bxy.xy, t);
            tmin[m] = fminf(fminf(t.x, t.y), tmin[m]);   // -> v_min3_f32
        }
    }

    // Merge partial mins across chunks (d >= 0 after clamp -> uint order == float order).
#pragma unroll
    for (int m = 0; m < MPTS; ++m) {
        const float d = fmaxf(tmin[m] + a2[m], 0.0f);
        atomicMin(&dmin[ibase + m], __float_as_uint(d));
    }

    // ---- last-block-reduces ----
    __threadfence();
    __syncthreads();
    __shared__ unsigned s_old;
    if (tid == 0) s_old = atomicAdd(counter, 1u);
    __syncthreads();
    if (s_old != CINIT + (unsigned)NBLOCKS - 1u) return;

    __threadfence();
    double s = 0.0;
    for (int i = tid; i < 2 * NPTS; i += BLOCK) {
        const unsigned bits = __hip_atomic_load(&dmin_all[i], __ATOMIC_RELAXED,
                                                __HIP_MEMORY_SCOPE_AGENT);
        s += (double)__uint_as_float(bits);
    }
    __shared__ double sd[BLOCK];
    sd[tid] = s;
    __syncthreads();
    for (int off = BLOCK / 2; off > 0; off >>= 1) {
        if (tid < off) sd[tid] += sd[tid + off];
        __syncthreads();
    }
    // mean(dist0) + mean(dist1) = (sum0 + sum1) / NPTS  (N0 == N1)
    if (tid == 0) out[0] = (float)(sd[0] / (double)NPTS);
}

extern "C" void kernel_launch(void* const* d_in, const int* in_sizes, int n_in,
                              void* d_out, int out_size, void* d_ws, size_t ws_size,
                              hipStream_t stream)
{
    const float* P0 = (const float*)d_in[0];
    const float* P1 = (const float*)d_in[1];
    float* out = (float*)d_out;
    unsigned* dmin = (unsigned*)d_ws;            // 2*NPTS partial mins
    unsigned* counter = dmin + 2 * NPTS;         // arrival counter (starts at 0x7F7F7F7F)

    // One memset covers dmin init (0x7F7F7F7F = 3.39e38 > any dist) AND the counter
    // (counts up from 0x7F7F7F7F; last block sees CINIT + NBLOCKS - 1).
    hipMemsetAsync(dmin, 0x7F, (size_t)(2 * NPTS + 1) * sizeof(unsigned), stream);

    dim3 grid(NATILES, NCHUNKS, 2);   // 16 x 32 x 2 = 1024 blocks
    chamfer_fused<<<grid, BLOCK, 0, stream>>>(P0, P1, dmin, counter, out);
}

// Round 3
// 112.278 us; speedup vs baseline: 1.1274x; 1.1274x over previous
//
#include <hip/hip_runtime.h>

// Chamfer (bidirectional 1-NN mean of squared distances), two [16384,3] fp32 clouds.
// d(i,j) = |a_i|^2 + (|b_j|^2 - 2 a_i.b_j); row-min taken on t(j)=|b_j|^2-2a.b_j.
//
// Round-3: revert to round-1 codegen idioms (float4 LDS element -> ONE ds_read_b128
// per B-point; scalar v_fma_f32). Round-2's packed-fp32 + swizzled-f32x4 reads
// doubled LDS instruction count and stalled (VALUBusy 98->23). Changes vs round-1:
//  - MPTS 4->8: halves LDS traffic per pair (round-1 was LDS/VALU co-saturated at
//    64/64 cyc per CU per B-point; now 64/112 -> purely VALU-bound).
//  - Process B-points in pairs, merge with v_min3_f32: 3.5 VALU instr/pair vs 4.
//  - Fused last-block reduce kept (1 memset + 1 kernel total).

#define NPTS 16384
#define CHUNK 512
#define NCHUNKS (NPTS / CHUNK)          // 32
#define MPTS 8                          // A-points per thread
#define BLOCK 256
#define APT (BLOCK * MPTS)              // 2048 A-points per block
#define NATILES (NPTS / APT)            // 8
#define NBLOCKS (NATILES * NCHUNKS * 2) // 512
#define CINIT 0x7F7F7F7Fu

__global__ __launch_bounds__(BLOCK) void chamfer_fused(
    const float* __restrict__ P0, const float* __restrict__ P1,
    unsigned* __restrict__ dmin_all, unsigned* __restrict__ counter,
    float* __restrict__ out)
{
    const float* A;
    const float* B;
    unsigned* dmin;
    if (blockIdx.z == 0) { A = P0; B = P1; dmin = dmin_all; }
    else                 { A = P1; B = P0; dmin = dmin_all + NPTS; }

    __shared__ float4 sB[CHUNK];   // {-2bx, -2by, -2bz, |b|^2} per B-point

    const int tid = threadIdx.x;

    // Stage this B-chunk into LDS, pre-transformed (identical idiom to round-1).
    const int bbase = blockIdx.y * CHUNK;
    for (int p = tid; p < CHUNK; p += BLOCK) {
        const float bx = B[(bbase + p) * 3 + 0];
        const float by = B[(bbase + p) * 3 + 1];
        const float bz = B[(bbase + p) * 3 + 2];
        sB[p] = make_float4(-2.0f * bx, -2.0f * by, -2.0f * bz,
                            bx * bx + by * by + bz * bz);
    }
    __syncthreads();

    // 8 A-points per thread.
    float ax[MPTS], ay[MPTS], az[MPTS], a2[MPTS], tmin[MPTS];
    const int ibase = blockIdx.x * APT + tid * MPTS;
#pragma unroll
    for (int m = 0; m < MPTS; ++m) {
        ax[m] = A[(ibase + m) * 3 + 0];
        ay[m] = A[(ibase + m) * 3 + 1];
        az[m] = A[(ibase + m) * 3 + 2];
        a2[m] = ax[m] * ax[m] + ay[m] * ay[m] + az[m] * az[m];
        tmin[m] = 3.0e38f;
    }

    // Inner loop: 2 broadcast ds_read_b128 per B-pair, then per A-point:
    // 6 v_fma_f32 + 1 v_min3_f32 = 3.5 VALU instr per pair.
#pragma unroll 2
    for (int q = 0; q < CHUNK / 2; ++q) {
        const float4 b0 = sB[2 * q];
        const float4 b1 = sB[2 * q + 1];
#pragma unroll
        for (int m = 0; m < MPTS; ++m) {
            float t0 = fmaf(az[m], b0.z, b0.w);
            t0 = fmaf(ay[m], b0.y, t0);
            t0 = fmaf(ax[m], b0.x, t0);
            float t1 = fmaf(az[m], b1.z, b1.w);
            t1 = fmaf(ay[m], b1.y, t1);
            t1 = fmaf(ax[m], b1.x, t1);
            tmin[m] = fminf(fminf(t0, t1), tmin[m]);   // -> v_min3_f32
        }
    }

    // Merge partial mins across chunks (d >= 0 after clamp -> uint order == float order).
#pragma unroll
    for (int m = 0; m < MPTS; ++m) {
        const float d = fmaxf(tmin[m] + a2[m], 0.0f);
        atomicMin(&dmin[ibase + m], __float_as_uint(d));
    }

    // ---- last-block-reduces ----
    __threadfence();
    __syncthreads();
    __shared__ unsigned s_old;
    if (tid == 0) s_old = atomicAdd(counter, 1u);
    __syncthreads();
    if (s_old != CINIT + (unsigned)NBLOCKS - 1u) return;

    __threadfence();
    double s = 0.0;
    for (int i = tid; i < 2 * NPTS; i += BLOCK) {
        const unsigned bits = __hip_atomic_load(&dmin_all[i], __ATOMIC_RELAXED,
                                                __HIP_MEMORY_SCOPE_AGENT);
        s += (double)__uint_as_float(bits);
    }
    __shared__ double sd[BLOCK];
    sd[tid] = s;
    __syncthreads();
    for (int off = BLOCK / 2; off > 0; off >>= 1) {
        if (tid < off) sd[tid] += sd[tid + off];
        __syncthreads();
    }
    // mean(dist0) + mean(dist1) = (sum0 + sum1) / NPTS  (N0 == N1)
    if (tid == 0) out[0] = (float)(sd[0] / (double)NPTS);
}

extern "C" void kernel_launch(void* const* d_in, const int* in_sizes, int n_in,
                              void* d_out, int out_size, void* d_ws, size_t ws_size,
                              hipStream_t stream)
{
    const float* P0 = (const float*)d_in[0];
    const float* P1 = (const float*)d_in[1];
    float* out = (float*)d_out;
    unsigned* dmin = (unsigned*)d_ws;            // 2*NPTS partial mins
    unsigned* counter = dmin + 2 * NPTS;         // arrival counter (starts at 0x7F7F7F7F)

    // One memset covers dmin init (0x7F7F7F7F = 3.39e38 > any dist) AND the counter
    // (counts up from 0x7F7F7F7F; last block sees CINIT + NBLOCKS - 1).
    hipMemsetAsync(dmin, 0x7F, (size_t)(2 * NPTS + 1) * sizeof(unsigned), stream);

    dim3 grid(NATILES, NCHUNKS, 2);   // 8 x 32 x 2 = 512 blocks
    chamfer_fused<<<grid, BLOCK, 0, stream>>>(P0, P1, dmin, counter, out);
}